// Round 1
// 749.997 us; speedup vs baseline: 1.6000x; 1.6000x over previous
//
#include <hip/hip_runtime.h>
#include <hip/hip_bf16.h>
#include <math.h>

#define NN 1024
#define ND 256
#define PSTRIDE 1288   // per-(b,chunk) partial block: 5*256 mu-acc + 5 colsum + pad

typedef __hip_bfloat16 bf;
__device__ __forceinline__ float bf2f(bf h) { return __bfloat162float(h); }

__device__ __forceinline__ float wave_reduce_sum(float v) {
#pragma unroll
    for (int off = 32; off > 0; off >>= 1) v += __shfl_down(v, off, 64);
    return v;
}
__device__ __forceinline__ float wave_allreduce_sum(float v) {
#pragma unroll
    for (int off = 1; off < 64; off <<= 1) v += __shfl_xor(v, off, 64);
    return v;
}

__global__ void zero_k(float* __restrict__ out) {
    int i = blockIdx.x * 1024 + threadIdx.x;
    out[(size_t)i * 8] = 0.f;
}

// ---------------- QL = query@W0^T+b0 ; KL = key@W1^T+b1 (bf16 out to ws) ----------------
__global__ __launch_bounds__(256) void gemm_k(
    const float* __restrict__ Aq, const float* __restrict__ Ak,
    const float* __restrict__ W0, const float* __restrict__ b0v,
    const float* __restrict__ W1, const float* __restrict__ b1v,
    bf* __restrict__ QL, bf* __restrict__ KL)
{
    const float* A; const float* Bw; const float* bias; bf* C;
    if (blockIdx.z == 0) { A = Aq; Bw = W0; bias = b0v; C = QL; }
    else                 { A = Ak; Bw = W1; bias = b1v; C = KL; }
    __shared__ float As[16][65];
    __shared__ float Bs[16][65];
    const int t = threadIdx.x;
    const int m0 = blockIdx.x * 64;
    const int n0 = blockIdx.y * 64;
    const int lm = t >> 2;
    const int lk = (t & 3) * 4;
    const int tr = (t >> 4) * 4;
    const int tc = (t & 15) * 4;
    float acc[4][4] = {};
    for (int k0 = 0; k0 < 256; k0 += 16) {
        float4 a4 = *(const float4*)(A + (size_t)(m0 + lm) * 256 + k0 + lk);
        float4 b4 = *(const float4*)(Bw + (size_t)(n0 + lm) * 256 + k0 + lk);
        __syncthreads();
        As[lk + 0][lm] = a4.x; As[lk + 1][lm] = a4.y; As[lk + 2][lm] = a4.z; As[lk + 3][lm] = a4.w;
        Bs[lk + 0][lm] = b4.x; Bs[lk + 1][lm] = b4.y; Bs[lk + 2][lm] = b4.z; Bs[lk + 3][lm] = b4.w;
        __syncthreads();
#pragma unroll
        for (int k = 0; k < 16; k++) {
            float av[4], bv[4];
#pragma unroll
            for (int i = 0; i < 4; i++) av[i] = As[k][tr + i];
#pragma unroll
            for (int j = 0; j < 4; j++) bv[j] = Bs[k][tc + j];
#pragma unroll
            for (int i = 0; i < 4; i++)
#pragma unroll
                for (int j = 0; j < 4; j++) acc[i][j] += av[i] * bv[j];
        }
    }
#pragma unroll
    for (int i = 0; i < 4; i++) {
        ushort4 pk;
        bf h0 = __float2bfloat16(acc[i][0] + bias[n0 + tc + 0]);
        bf h1 = __float2bfloat16(acc[i][1] + bias[n0 + tc + 1]);
        bf h2 = __float2bfloat16(acc[i][2] + bias[n0 + tc + 2]);
        bf h3 = __float2bfloat16(acc[i][3] + bias[n0 + tc + 3]);
        pk.x = *(unsigned short*)&h0; pk.y = *(unsigned short*)&h1;
        pk.z = *(unsigned short*)&h2; pk.w = *(unsigned short*)&h3;
        *(ushort4*)&C[(size_t)(m0 + tr + i) * 256 + n0 + tc] = pk;
    }
}

// ---------------- flash attention from materialized bf16 QL/KL ----------------
__global__ __launch_bounds__(256) void attn2_k(
    const bf* __restrict__ QL, const bf* __restrict__ KL,
    const float* __restrict__ value, const float* __restrict__ lamda,
    float* __restrict__ out)
{
    int bh = blockIdx.x; int b = bh >> 3, h = bh & 7;
    int t = threadIdx.x;
    int q = blockIdx.y * 256 + t;
    const float scale = 0.17677669529663687f;
    __shared__ float kv[128 * 32];
    __shared__ float vv[128];
    float qreg[32];
    {
        const bf* qrow = QL + ((size_t)b * NN + q) * ND + h * 32;
#pragma unroll
        for (int p = 0; p < 4; p++) {
            float4 raw = ((const float4*)qrow)[p];
            const bf* hb = (const bf*)&raw;
#pragma unroll
            for (int j = 0; j < 8; j++) qreg[p * 8 + j] = bf2f(hb[j]);
        }
    }
    float m = -3.0e38f, l = 0.f, acc = 0.f, wsacc = 0.f;
    for (int kt = 0; kt < 8; kt++) {
        __syncthreads();
#pragma unroll
        for (int i = 0; i < 2; i++) {
            int s = t + i * 256;
            int row = s >> 2, seg = s & 3;
            float4 raw = *(const float4*)&KL[((size_t)b * NN + kt * 128 + row) * ND + h * 32 + seg * 8];
            const bf* hb = (const bf*)&raw;
#pragma unroll
            for (int j = 0; j < 8; j++) kv[row * 32 + seg * 8 + j] = bf2f(hb[j]);
        }
        if (t < 128) vv[t] = value[(size_t)b * NN + kt * 128 + t];
        __syncthreads();
        for (int r = 0; r < 128; r++) {
            const float* kr = &kv[r * 32];
            float dot = 0.f;
#pragma unroll
            for (int j4 = 0; j4 < 8; j4++) {
                float4 kx = *(const float4*)&kr[j4 * 4];
                dot += qreg[j4*4+0]*kx.x + qreg[j4*4+1]*kx.y + qreg[j4*4+2]*kx.z + qreg[j4*4+3]*kx.w;
            }
            wsacc += dot * vv[r];
            float s = dot * scale;
            float nm = fmaxf(m, s);
            float p = expf(s - nm);
            float cor = expf(m - nm);
            l = l * cor + p;
            acc = acc * cor + p * vv[r];
            m = nm;
        }
    }
    float part = acc / l;
    float whole = fmaxf(wsacc * scale * (1.0f / 1024.0f), 0.f);
    float lam = lamda[0];
    float f = ((1.f - lam) * part + lam * whole) * 0.125f;
    atomicAdd(&out[((size_t)b * NN + q) * 8], f);
}

// ---------------- one phase-A PMMS stage: grid (16 chunks, 16 batches) x 256 ----------------
// stage s: reduce pin partials -> mu_s (redundant per block), z from mu_s for this chunk's
// 64 rows, write partial mu-accumulator + partial colsum to pout.
__global__ __launch_bounds__(256) void pmms_a_k(
    const float* __restrict__ query, const float* __restrict__ mu0a,
    const float* __restrict__ pin, float* __restrict__ pout, int stage)
{
    __shared__ float muT[5 * 256];    // [k][c]
    __shared__ float z_s[64][8];      // [n_local][k], padded for float4
    __shared__ float red[32];
    int chunk = blockIdx.x, b = blockIdx.y;
    int t = threadIdx.x;
    int wave = t >> 6, lane = t & 63;

    if (stage == 0) {
        for (int idx = t; idx < 1280; idx += 256)
            muT[idx] = mu0a[(idx & 255) * 5 + (idx >> 8)];
    } else {
        float mr[5] = {0,0,0,0,0};
        float cs[5] = {0,0,0,0,0};
        for (int ch = 0; ch < 16; ch++) {
            const float* pb = pin + ((size_t)(b * 16 + ch)) * PSTRIDE;
#pragma unroll
            for (int k = 0; k < 5; k++) mr[k] += pb[k * 256 + t];
#pragma unroll
            for (int k = 0; k < 5; k++) cs[k] += pb[1280 + k];
        }
#pragma unroll
        for (int k = 0; k < 5; k++) mr[k] *= 1.0f / (1e-6f + cs[k]);
#pragma unroll
        for (int k = 0; k < 5; k++) {
            float s = wave_reduce_sum(mr[k] * mr[k]);
            if (lane == 0) red[wave * 5 + k] = s;
        }
        __syncthreads();
        if (t < 5) red[20 + t] = 1.0f / (1e-6f + sqrtf(red[t] + red[5 + t] + red[10 + t] + red[15 + t]));
        __syncthreads();
#pragma unroll
        for (int k = 0; k < 5; k++) muT[k * 256 + t] = mr[k] * red[20 + k];
    }
    __syncthreads();

    // z for 64 rows: 4 lanes per row, each covering 64 c's
    int n_local = t >> 2, part = t & 3;
    int n = chunk * 64 + n_local;
    const float* qrow = query + ((size_t)b * NN + n) * ND + part * 64;
    float lg[5] = {0,0,0,0,0};
#pragma unroll
    for (int c4 = 0; c4 < 64; c4 += 4) {
        float4 qv = *(const float4*)&qrow[c4];
#pragma unroll
        for (int k = 0; k < 5; k++) {
            float4 mv = *(const float4*)&muT[k * 256 + part * 64 + c4];
            lg[k] += qv.x*mv.x + qv.y*mv.y + qv.z*mv.z + qv.w*mv.w;
        }
    }
#pragma unroll
    for (int k = 0; k < 5; k++) {
        lg[k] += __shfl_xor(lg[k], 1, 64);
        lg[k] += __shfl_xor(lg[k], 2, 64);
    }
    float mx = lg[0];
#pragma unroll
    for (int k = 1; k < 5; k++) mx = fmaxf(mx, lg[k]);
    float e[5], ssum = 0.f;
#pragma unroll
    for (int k = 0; k < 5; k++) { e[k] = expf(20.0f * (lg[k] - mx)); ssum += e[k]; }
    float is = 1.0f / ssum;
    if (part == 0) {
#pragma unroll
        for (int k = 0; k < 5; k++) z_s[n_local][k] = e[k] * is;
    }
    __syncthreads();

    // partial mu accumulation: thread owns c = t
    float pa[5] = {0,0,0,0,0};
    const float* qcol = query + ((size_t)b * NN + chunk * 64) * ND + t;
#pragma unroll 4
    for (int nl = 0; nl < 64; nl++) {
        float qv = qcol[(size_t)nl * ND];
        float4 z4 = *(const float4*)&z_s[nl][0];
        float z4v = z_s[nl][4];
        pa[0] += qv * z4.x; pa[1] += qv * z4.y; pa[2] += qv * z4.z;
        pa[3] += qv * z4.w; pa[4] += qv * z4v;
    }
    float* pb = pout + ((size_t)(b * 16 + chunk)) * PSTRIDE;
#pragma unroll
    for (int k = 0; k < 5; k++) pb[k * 256 + t] = pa[k];
    if (t < 5) {
        float s = 0.f;
        for (int nl = 0; nl < 64; nl++) s += z_s[nl][t];
        pb[1280 + t] = s;
    }
}

// ---------------- phase B: wave-synchronous, one 64-thread block per batch ----------------
__global__ __launch_bounds__(64) void pmms_b_k(
    const float* __restrict__ pin, const float* __restrict__ mu0b,
    float* __restrict__ m1_ws, float* __restrict__ mu2_ws)
{
    int b = blockIdx.x, lane = threadIdx.x;
    float nd[5][4];
    float cs[5] = {0,0,0,0,0};
#pragma unroll
    for (int n = 0; n < 5; n++)
#pragma unroll
        for (int j = 0; j < 4; j++) nd[n][j] = 0.f;
    for (int ch = 0; ch < 16; ch++) {
        const float* pb = pin + ((size_t)(b * 16 + ch)) * PSTRIDE;
#pragma unroll
        for (int n = 0; n < 5; n++)
#pragma unroll
            for (int j = 0; j < 4; j++) nd[n][j] += pb[n * 256 + lane + 64 * j];
#pragma unroll
        for (int n = 0; n < 5; n++) cs[n] += pb[1280 + n];
    }
#pragma unroll
    for (int n = 0; n < 5; n++) {
        float inv = 1.0f / (1e-6f + cs[n]);
        float sq = 0.f;
#pragma unroll
        for (int j = 0; j < 4; j++) { nd[n][j] *= inv; sq += nd[n][j] * nd[n][j]; }
        float s = wave_allreduce_sum(sq);
        float nr = 1.0f / (1e-6f + sqrtf(s));
#pragma unroll
        for (int j = 0; j < 4; j++) {
            nd[n][j] *= nr;
            m1_ws[((size_t)b * 5 + n) * 256 + lane + 64 * j] = nd[n][j];
        }
    }
    float mu[2][4];
#pragma unroll
    for (int k = 0; k < 2; k++)
#pragma unroll
        for (int j = 0; j < 4; j++) mu[k][j] = mu0b[(lane + 64 * j) * 2 + k];
    for (int stage = 0; stage < 10; stage++) {
        float z[5][2];
        float colsum0 = 0.f, colsum1 = 0.f;
#pragma unroll
        for (int n = 0; n < 5; n++) {
            float l0 = 0.f, l1 = 0.f;
#pragma unroll
            for (int j = 0; j < 4; j++) { l0 += nd[n][j] * mu[0][j]; l1 += nd[n][j] * mu[1][j]; }
            l0 = wave_allreduce_sum(l0);
            l1 = wave_allreduce_sum(l1);
            float a0 = 20.0f * l0, a1 = 20.0f * l1;
            float mxv = fmaxf(a0, a1);
            float e0 = expf(a0 - mxv), e1 = expf(a1 - mxv);
            float inv = 1.0f / (e0 + e1);
            z[n][0] = e0 * inv; z[n][1] = e1 * inv;
            colsum0 += z[n][0]; colsum1 += z[n][1];
        }
        float i0 = 1.0f / (1e-6f + colsum0), i1 = 1.0f / (1e-6f + colsum1);
#pragma unroll
        for (int k = 0; k < 2; k++) {
            float iv = k ? i1 : i0;
            float sq = 0.f;
            float nm[4];
#pragma unroll
            for (int j = 0; j < 4; j++) {
                float v = 0.f;
#pragma unroll
                for (int n = 0; n < 5; n++) v += nd[n][j] * z[n][k];
                v *= iv;
                nm[j] = v; sq += v * v;
            }
            float s = wave_allreduce_sum(sq);
            float nr = 1.0f / (1e-6f + sqrtf(s));
#pragma unroll
            for (int j = 0; j < 4; j++) mu[k][j] = nm[j] * nr;
        }
    }
#pragma unroll
    for (int k = 0; k < 2; k++)
#pragma unroll
        for (int j = 0; j < 4; j++) mu2_ws[((size_t)b * 2 + k) * 256 + lane + 64 * j] = mu[k][j];
}

// ---------------- P1 = softmax(q.m1), P2 = softmax(q.mu2) ----------------
__global__ __launch_bounds__(256) void pmap_k(
    const float* __restrict__ query, const float* __restrict__ m1_ws,
    const float* __restrict__ mu2_ws, float* __restrict__ P1, float* __restrict__ P2)
{
    __shared__ float ms[7 * 256];
    int b = blockIdx.y;
    int t = threadIdx.x;
    int n = blockIdx.x * 256 + t;
    for (int idx = t; idx < 1280; idx += 256) ms[idx] = m1_ws[(size_t)b * 1280 + idx];
    for (int idx = t; idx < 512; idx += 256) ms[1280 + idx] = mu2_ws[(size_t)b * 512 + idx];
    __syncthreads();
    const float* qrow = query + ((size_t)b * NN + n) * ND;
    float lg[7] = {0,0,0,0,0,0,0};
    for (int c4 = 0; c4 < 256; c4 += 4) {
        float4 qv = *(const float4*)&qrow[c4];
#pragma unroll
        for (int k = 0; k < 7; k++) {
            float4 mv = *(const float4*)&ms[k * 256 + c4];
            lg[k] += qv.x*mv.x + qv.y*mv.y + qv.z*mv.z + qv.w*mv.w;
        }
    }
    float mx = lg[0];
#pragma unroll
    for (int k = 1; k < 5; k++) mx = fmaxf(mx, lg[k]);
    float e[5], ssum = 0.f;
#pragma unroll
    for (int k = 0; k < 5; k++) { e[k] = expf(lg[k] - mx); ssum += e[k]; }
    float is = 1.0f / ssum;
#pragma unroll
    for (int k = 0; k < 5; k++) P1[((size_t)b * 5 + k) * NN + n] = e[k] * is;
    float mx2 = fmaxf(lg[5], lg[6]);
    float e0 = expf(lg[5] - mx2), e1 = expf(lg[6] - mx2);
    float inv = 1.0f / (e0 + e1);
    P2[((size_t)b * 2 + 0) * NN + n] = e0 * inv;
    P2[((size_t)b * 2 + 1) * NN + n] = e1 * inv;
}

// ---------------- node_weight conv: one (b, ch) per block, 3 barriers total ----------------
__global__ __launch_bounds__(1024) void nwconv_k(
    const float* __restrict__ P1, const float* __restrict__ P2,
    const float* __restrict__ w1a, const float* __restrict__ b1a,
    const float* __restrict__ ga,  const float* __restrict__ bea,
    const float* __restrict__ w2a, const float* __restrict__ b2a,
    const float* __restrict__ w1b, const float* __restrict__ b1b,
    const float* __restrict__ gb,  const float* __restrict__ beb,
    const float* __restrict__ w2b, const float* __restrict__ b2b,
    float* __restrict__ out)
{
    __shared__ float img[34 * 34];
    __shared__ float mid[16][34 * 34];
    __shared__ float w1s[144], w2s[144], bs[16], gs[16], bes[16], b2s[1];
    int ch = blockIdx.x, b = blockIdx.y;
    int t = threadIdx.x;
    int i = t >> 5, j = t & 31;
    const float* xsrc = (ch < 5) ? &P1[((size_t)b * 5 + ch) * NN]
                                 : &P2[((size_t)b * 2 + (ch - 5)) * NN];
    if (t < 144) { w1s[t] = (ch < 5 ? w1a : w1b)[t]; w2s[t] = (ch < 5 ? w2a : w2b)[t]; }
    if (t >= 256 && t < 272) {
        int y = t - 256;
        bs[y] = (ch < 5 ? b1a : b1b)[y];
        gs[y] = (ch < 5 ? ga : gb)[y];
        bes[y] = (ch < 5 ? bea : beb)[y];
    }
    if (t == 512) b2s[0] = (ch < 5 ? b2a : b2b)[0];
    for (int idx = t; idx < 1156; idx += 1024) img[idx] = 0.f;
    for (int idx = t; idx < 16 * 1156; idx += 1024) ((float*)mid)[idx] = 0.f;
    __syncthreads();
    float xv = xsrc[t];
    img[(i + 1) * 34 + (j + 1)] = xv;
    __syncthreads();
    float r[9];
#pragma unroll
    for (int dy = 0; dy < 3; dy++)
#pragma unroll
        for (int dx = 0; dx < 3; dx++)
            r[dy * 3 + dx] = img[(i + dy) * 34 + (j + dx)];
    const float bninv = rsqrtf(1.0f + 1e-5f);
#pragma unroll
    for (int oc = 0; oc < 16; oc++) {
        float a = 0.f;
#pragma unroll
        for (int q2 = 0; q2 < 9; q2++) a += w1s[oc * 9 + q2] * r[q2];
        a += bs[oc];
        a = gs[oc] * (a * bninv) + bes[oc];
        a = fmaxf(a, 0.f);
        mid[oc][(i + 1) * 34 + (j + 1)] = a;
    }
    __syncthreads();
    float acc2 = b2s[0];
#pragma unroll
    for (int oc = 0; oc < 16; oc++)
#pragma unroll
        for (int dy = 0; dy < 3; dy++)
#pragma unroll
            for (int dx = 0; dx < 3; dx++)
                acc2 += w2s[oc * 9 + dy * 3 + dx] * mid[oc][(i + dy) * 34 + (j + dx)];
    float sig = 1.0f / (1.0f + expf(-acc2));
    out[((size_t)(b * NN + t)) * 8 + 1 + ch] = xv * sig;
}

extern "C" void kernel_launch(void* const* d_in, const int* in_sizes, int n_in,
                              void* d_out, int out_size, void* d_ws, size_t ws_size,
                              hipStream_t stream) {
    const float* query = (const float*)d_in[0];
    const float* key   = (const float*)d_in[1];
    const float* value = (const float*)d_in[2];
    const float* lamda = (const float*)d_in[3];
    const float* W0 = (const float*)d_in[4];
    const float* b0 = (const float*)d_in[5];
    const float* W1 = (const float*)d_in[6];
    const float* b1 = (const float*)d_in[7];
    const float* mu_a = (const float*)d_in[8];
    const float* mu_b = (const float*)d_in[9];
    const float* nw1_w1 = (const float*)d_in[10];
    const float* nw1_b1 = (const float*)d_in[11];
    const float* nw1_g  = (const float*)d_in[12];
    const float* nw1_be = (const float*)d_in[13];
    const float* nw1_w2 = (const float*)d_in[14];
    const float* nw1_b2 = (const float*)d_in[15];
    const float* nw2_w1 = (const float*)d_in[16];
    const float* nw2_b1 = (const float*)d_in[17];
    const float* nw2_g  = (const float*)d_in[18];
    const float* nw2_be = (const float*)d_in[19];
    const float* nw2_w2 = (const float*)d_in[20];
    const float* nw2_b2 = (const float*)d_in[21];
    float* out = (float*)d_out;

    // ws: QLb [0,8MB) + KLb [8,16MB) as bf16 (attention path).
    bf* QLb = (bf*)d_ws;
    bf* KLb = (bf*)((char*)d_ws + ((size_t)8 << 20));
    // PMMS scratch (~3.2 MB) OVERLAYS the QLb region. Safe: attn2_k (last consumer of
    // QLb/KLb) completes before the first pmms_a_k launch on the serialized stream.
    float* PA   = (float*)d_ws;
    float* PB   = PA + (size_t)16 * 16 * PSTRIDE;
    float* m1w  = PB + (size_t)16 * 16 * PSTRIDE;
    float* mu2w = m1w + (size_t)16 * 1280;
    float* P1w  = mu2w + (size_t)16 * 512;
    float* P2w  = P1w + (size_t)16 * 5 * 1024;

    zero_k<<<16, 1024, 0, stream>>>(out);
    gemm_k<<<dim3(256, 4, 2), 256, 0, stream>>>(query, key, W0, b0, W1, b1, QLb, KLb);
    attn2_k<<<dim3(128, 4), 256, 0, stream>>>(QLb, KLb, value, lamda, out);
    for (int s = 0; s < 10; s++) {
        const float* pin = (s & 1) ? PA : PB;
        float* pout      = (s & 1) ? PB : PA;
        pmms_a_k<<<dim3(16, 16), 256, 0, stream>>>(query, mu_a, pin, pout, s);
    }
    pmms_b_k<<<16, 64, 0, stream>>>(PB, mu_b, m1w, mu2w);
    pmap_k<<<dim3(4, 16), 256, 0, stream>>>(query, m1w, mu2w, P1w, P2w);
    nwconv_k<<<dim3(7, 16), 1024, 0, stream>>>(P1w, P2w,
                                    nw1_w1, nw1_b1, nw1_g, nw1_be, nw1_w2, nw1_b2,
                                    nw2_w1, nw2_b1, nw2_g, nw2_be, nw2_w2, nw2_b2, out);
}

// Round 2
// 426.319 us; speedup vs baseline: 2.8147x; 1.7592x over previous
//
#include <hip/hip_runtime.h>
#include <hip/hip_bf16.h>
#include <math.h>

#define NN 1024
#define ND 256
#define PSTRIDE 1288   // per-(b,chunk) partial block: 5*256 mu-acc + 5 colsum + pad

typedef __hip_bfloat16 bf;
__device__ __forceinline__ float bf2f(bf h) { return __bfloat162float(h); }

typedef __attribute__((ext_vector_type(8))) short bf16x8;
typedef __attribute__((ext_vector_type(4))) float f32x4;

__device__ __forceinline__ float wave_reduce_sum(float v) {
#pragma unroll
    for (int off = 32; off > 0; off >>= 1) v += __shfl_down(v, off, 64);
    return v;
}
__device__ __forceinline__ float wave_allreduce_sum(float v) {
#pragma unroll
    for (int off = 1; off < 64; off <<= 1) v += __shfl_xor(v, off, 64);
    return v;
}

__global__ void zero_k(float* __restrict__ out) {
    int i = blockIdx.x * 1024 + threadIdx.x;
    out[(size_t)i * 8] = 0.f;
}

// ---------------- QL = query@W0^T+b0 ; KL = key@W1^T+b1 (bf16 out to ws) ----------------
__global__ __launch_bounds__(256) void gemm_k(
    const float* __restrict__ Aq, const float* __restrict__ Ak,
    const float* __restrict__ W0, const float* __restrict__ b0v,
    const float* __restrict__ W1, const float* __restrict__ b1v,
    bf* __restrict__ QL, bf* __restrict__ KL)
{
    const float* A; const float* Bw; const float* bias; bf* C;
    if (blockIdx.z == 0) { A = Aq; Bw = W0; bias = b0v; C = QL; }
    else                 { A = Ak; Bw = W1; bias = b1v; C = KL; }
    __shared__ float As[16][65];
    __shared__ float Bs[16][65];
    const int t = threadIdx.x;
    const int m0 = blockIdx.x * 64;
    const int n0 = blockIdx.y * 64;
    const int lm = t >> 2;
    const int lk = (t & 3) * 4;
    const int tr = (t >> 4) * 4;
    const int tc = (t & 15) * 4;
    float acc[4][4] = {};
    for (int k0 = 0; k0 < 256; k0 += 16) {
        float4 a4 = *(const float4*)(A + (size_t)(m0 + lm) * 256 + k0 + lk);
        float4 b4 = *(const float4*)(Bw + (size_t)(n0 + lm) * 256 + k0 + lk);
        __syncthreads();
        As[lk + 0][lm] = a4.x; As[lk + 1][lm] = a4.y; As[lk + 2][lm] = a4.z; As[lk + 3][lm] = a4.w;
        Bs[lk + 0][lm] = b4.x; Bs[lk + 1][lm] = b4.y; Bs[lk + 2][lm] = b4.z; Bs[lk + 3][lm] = b4.w;
        __syncthreads();
#pragma unroll
        for (int k = 0; k < 16; k++) {
            float av[4], bv[4];
#pragma unroll
            for (int i = 0; i < 4; i++) av[i] = As[k][tr + i];
#pragma unroll
            for (int j = 0; j < 4; j++) bv[j] = Bs[k][tc + j];
#pragma unroll
            for (int i = 0; i < 4; i++)
#pragma unroll
                for (int j = 0; j < 4; j++) acc[i][j] += av[i] * bv[j];
        }
    }
#pragma unroll
    for (int i = 0; i < 4; i++) {
        ushort4 pk;
        bf h0 = __float2bfloat16(acc[i][0] + bias[n0 + tc + 0]);
        bf h1 = __float2bfloat16(acc[i][1] + bias[n0 + tc + 1]);
        bf h2 = __float2bfloat16(acc[i][2] + bias[n0 + tc + 2]);
        bf h3 = __float2bfloat16(acc[i][3] + bias[n0 + tc + 3]);
        pk.x = *(unsigned short*)&h0; pk.y = *(unsigned short*)&h1;
        pk.z = *(unsigned short*)&h2; pk.w = *(unsigned short*)&h3;
        *(ushort4*)&C[(size_t)(m0 + tr + i) * 256 + n0 + tc] = pk;
    }
}

// ---------------- MFMA flash attention from materialized bf16 QL/KL ----------------
// Per wave: 64 q-rows (4 A-fragments of 16x32). K staged per 128-k tile in LDS in
// MFMA fragment order (lane-linear ds_read_b128, zero bank conflicts). value is a
// per-k scalar, so "PV" is a row-accumulation of exp(s*scale) and exp(s*scale)*v
// plus s*v for the `whole` term. Softmax is shift-invariant and |s| is O(1) here,
// so no running max -> no serial dependency chain.
__global__ __launch_bounds__(256) void attn3_k(
    const bf* __restrict__ QL, const bf* __restrict__ KL,
    const float* __restrict__ value, const float* __restrict__ lamda,
    float* __restrict__ out)
{
    const int bh = blockIdx.x; const int b = bh >> 3, h = bh & 7;
    const int t = threadIdx.x;
    const int wave = t >> 6, lane = t & 63;
    const int q0 = blockIdx.y * 256 + wave * 64;
    const float scale = 0.17677669529663687f;

    __shared__ bf Kf[128 * 32];   // 512 fragments * 8 bf16, fragment order
    __shared__ float vv[128];

    // Q fragments direct from global: lane l -> row q0+m*16+(l&15), k-chunk (l>>4)*8
    bf16x8 qf[4];
    {
        const bf* qbase = QL + ((size_t)b * NN) * ND + h * 32 + (lane >> 4) * 8;
#pragma unroll
        for (int m = 0; m < 4; m++)
            qf[m] = *(const bf16x8*)(qbase + (size_t)(q0 + m * 16 + (lane & 15)) * ND);
    }
    f32x4 lsum[4], vacc[4], wacc[4];
#pragma unroll
    for (int m = 0; m < 4; m++)
#pragma unroll
        for (int r = 0; r < 4; r++) { lsum[m][r] = 0.f; vacc[m][r] = 0.f; wacc[m][r] = 0.f; }

    const bf* kbase = KL + ((size_t)b * NN) * ND + h * 32;
    for (int kt = 0; kt < 8; kt++) {
        const int k0 = kt * 128;
        __syncthreads();
        // stage 512 fragments: f -> tile f>>6, chunk (f>>4)&3, row f&15; LDS addr f*16B
#pragma unroll
        for (int i = 0; i < 2; i++) {
            int f = t + i * 256;
            int row = ((f >> 6) << 4) + (f & 15);
            int chunk = (f >> 4) & 3;
            *(bf16x8*)&Kf[f * 8] = *(const bf16x8*)(kbase + (size_t)(k0 + row) * ND + chunk * 8);
        }
        if (t < 128) vv[t] = value[(size_t)b * NN + k0 + t];
        __syncthreads();
#pragma unroll
        for (int s = 0; s < 8; s++) {
            bf16x8 bfr = *(const bf16x8*)&Kf[(s * 64 + lane) * 8];
            float vcol = vv[s * 16 + (lane & 15)];
#pragma unroll
            for (int m = 0; m < 4; m++) {
                f32x4 acc = {0.f, 0.f, 0.f, 0.f};
                acc = __builtin_amdgcn_mfma_f32_16x16x32_bf16(qf[m], bfr, acc, 0, 0, 0);
#pragma unroll
                for (int r = 0; r < 4; r++) {
                    float sraw = acc[r];
                    float p = __expf(sraw * scale);
                    lsum[m][r] += p;
                    vacc[m][r] += p * vcol;
                    wacc[m][r] += sraw * vcol;
                }
            }
        }
    }
    // row reduce across the 16 col-lanes; D layout: col=lane&15, row=(lane>>4)*4+r
    const float lam = lamda[0];
#pragma unroll
    for (int m = 0; m < 4; m++)
#pragma unroll
        for (int r = 0; r < 4; r++) {
            float ls = lsum[m][r], va = vacc[m][r], wa = wacc[m][r];
#pragma unroll
            for (int off = 1; off < 16; off <<= 1) {
                ls += __shfl_xor(ls, off, 64);
                va += __shfl_xor(va, off, 64);
                wa += __shfl_xor(wa, off, 64);
            }
            if ((lane & 15) == 0) {
                int q = q0 + m * 16 + (lane >> 4) * 4 + r;
                float part = va / ls;
                float whole = fmaxf(wa * scale * (1.0f / 1024.0f), 0.f);
                float f = ((1.f - lam) * part + lam * whole) * 0.125f;
                atomicAdd(&out[((size_t)b * NN + q) * 8], f);
            }
        }
}

// ---------------- one phase-A PMMS stage: grid (16 chunks, 16 batches) x 256 ----------------
__global__ __launch_bounds__(256) void pmms_a_k(
    const float* __restrict__ query, const float* __restrict__ mu0a,
    const float* __restrict__ pin, float* __restrict__ pout, int stage)
{
    __shared__ float muT[5 * 256];    // [k][c]
    __shared__ float z_s[64][8];      // [n_local][k], padded for float4
    __shared__ float red[32];
    int chunk = blockIdx.x, b = blockIdx.y;
    int t = threadIdx.x;
    int wave = t >> 6, lane = t & 63;

    if (stage == 0) {
        for (int idx = t; idx < 1280; idx += 256)
            muT[idx] = mu0a[(idx & 255) * 5 + (idx >> 8)];
    } else {
        float mr[5] = {0,0,0,0,0};
        float cs[5] = {0,0,0,0,0};
        for (int ch = 0; ch < 16; ch++) {
            const float* pb = pin + ((size_t)(b * 16 + ch)) * PSTRIDE;
#pragma unroll
            for (int k = 0; k < 5; k++) mr[k] += pb[k * 256 + t];
#pragma unroll
            for (int k = 0; k < 5; k++) cs[k] += pb[1280 + k];
        }
#pragma unroll
        for (int k = 0; k < 5; k++) mr[k] *= 1.0f / (1e-6f + cs[k]);
#pragma unroll
        for (int k = 0; k < 5; k++) {
            float s = wave_reduce_sum(mr[k] * mr[k]);
            if (lane == 0) red[wave * 5 + k] = s;
        }
        __syncthreads();
        if (t < 5) red[20 + t] = 1.0f / (1e-6f + sqrtf(red[t] + red[5 + t] + red[10 + t] + red[15 + t]));
        __syncthreads();
#pragma unroll
        for (int k = 0; k < 5; k++) muT[k * 256 + t] = mr[k] * red[20 + k];
    }
    __syncthreads();

    // z for 64 rows: 4 lanes per row, each covering 64 c's
    int n_local = t >> 2, part = t & 3;
    int n = chunk * 64 + n_local;
    const float* qrow = query + ((size_t)b * NN + n) * ND + part * 64;
    float lg[5] = {0,0,0,0,0};
#pragma unroll
    for (int c4 = 0; c4 < 64; c4 += 4) {
        float4 qv = *(const float4*)&qrow[c4];
#pragma unroll
        for (int k = 0; k < 5; k++) {
            float4 mv = *(const float4*)&muT[k * 256 + part * 64 + c4];
            lg[k] += qv.x*mv.x + qv.y*mv.y + qv.z*mv.z + qv.w*mv.w;
        }
    }
#pragma unroll
    for (int k = 0; k < 5; k++) {
        lg[k] += __shfl_xor(lg[k], 1, 64);
        lg[k] += __shfl_xor(lg[k], 2, 64);
    }
    float mx = lg[0];
#pragma unroll
    for (int k = 1; k < 5; k++) mx = fmaxf(mx, lg[k]);
    float e[5], ssum = 0.f;
#pragma unroll
    for (int k = 0; k < 5; k++) { e[k] = expf(20.0f * (lg[k] - mx)); ssum += e[k]; }
    float is = 1.0f / ssum;
    if (part == 0) {
#pragma unroll
        for (int k = 0; k < 5; k++) z_s[n_local][k] = e[k] * is;
    }
    __syncthreads();

    // partial mu accumulation: thread owns c = t
    float pa[5] = {0,0,0,0,0};
    const float* qcol = query + ((size_t)b * NN + chunk * 64) * ND + t;
#pragma unroll 4
    for (int nl = 0; nl < 64; nl++) {
        float qv = qcol[(size_t)nl * ND];
        float4 z4 = *(const float4*)&z_s[nl][0];
        float z4v = z_s[nl][4];
        pa[0] += qv * z4.x; pa[1] += qv * z4.y; pa[2] += qv * z4.z;
        pa[3] += qv * z4.w; pa[4] += qv * z4v;
    }
    float* pb = pout + ((size_t)(b * 16 + chunk)) * PSTRIDE;
#pragma unroll
    for (int k = 0; k < 5; k++) pb[k * 256 + t] = pa[k];
    if (t < 5) {
        float s = 0.f;
        for (int nl = 0; nl < 64; nl++) s += z_s[nl][t];
        pb[1280 + t] = s;
    }
}

// ---------------- phase B: wave-synchronous, one 64-thread block per batch ----------------
__global__ __launch_bounds__(64) void pmms_b_k(
    const float* __restrict__ pin, const float* __restrict__ mu0b,
    float* __restrict__ m1_ws, float* __restrict__ mu2_ws)
{
    int b = blockIdx.x, lane = threadIdx.x;
    float nd[5][4];
    float cs[5] = {0,0,0,0,0};
#pragma unroll
    for (int n = 0; n < 5; n++)
#pragma unroll
        for (int j = 0; j < 4; j++) nd[n][j] = 0.f;
    for (int ch = 0; ch < 16; ch++) {
        const float* pb = pin + ((size_t)(b * 16 + ch)) * PSTRIDE;
#pragma unroll
        for (int n = 0; n < 5; n++)
#pragma unroll
            for (int j = 0; j < 4; j++) nd[n][j] += pb[n * 256 + lane + 64 * j];
#pragma unroll
        for (int n = 0; n < 5; n++) cs[n] += pb[1280 + n];
    }
#pragma unroll
    for (int n = 0; n < 5; n++) {
        float inv = 1.0f / (1e-6f + cs[n]);
        float sq = 0.f;
#pragma unroll
        for (int j = 0; j < 4; j++) { nd[n][j] *= inv; sq += nd[n][j] * nd[n][j]; }
        float s = wave_allreduce_sum(sq);
        float nr = 1.0f / (1e-6f + sqrtf(s));
#pragma unroll
        for (int j = 0; j < 4; j++) {
            nd[n][j] *= nr;
            m1_ws[((size_t)b * 5 + n) * 256 + lane + 64 * j] = nd[n][j];
        }
    }
    float mu[2][4];
#pragma unroll
    for (int k = 0; k < 2; k++)
#pragma unroll
        for (int j = 0; j < 4; j++) mu[k][j] = mu0b[(lane + 64 * j) * 2 + k];
    for (int stage = 0; stage < 10; stage++) {
        float z[5][2];
        float colsum0 = 0.f, colsum1 = 0.f;
#pragma unroll
        for (int n = 0; n < 5; n++) {
            float l0 = 0.f, l1 = 0.f;
#pragma unroll
            for (int j = 0; j < 4; j++) { l0 += nd[n][j] * mu[0][j]; l1 += nd[n][j] * mu[1][j]; }
            l0 = wave_allreduce_sum(l0);
            l1 = wave_allreduce_sum(l1);
            float a0 = 20.0f * l0, a1 = 20.0f * l1;
            float mxv = fmaxf(a0, a1);
            float e0 = expf(a0 - mxv), e1 = expf(a1 - mxv);
            float inv = 1.0f / (e0 + e1);
            z[n][0] = e0 * inv; z[n][1] = e1 * inv;
            colsum0 += z[n][0]; colsum1 += z[n][1];
        }
        float i0 = 1.0f / (1e-6f + colsum0), i1 = 1.0f / (1e-6f + colsum1);
#pragma unroll
        for (int k = 0; k < 2; k++) {
            float iv = k ? i1 : i0;
            float sq = 0.f;
            float nm[4];
#pragma unroll
            for (int j = 0; j < 4; j++) {
                float v = 0.f;
#pragma unroll
                for (int n = 0; n < 5; n++) v += nd[n][j] * z[n][k];
                v *= iv;
                nm[j] = v; sq += v * v;
            }
            float s = wave_allreduce_sum(sq);
            float nr = 1.0f / (1e-6f + sqrtf(s));
#pragma unroll
            for (int j = 0; j < 4; j++) mu[k][j] = nm[j] * nr;
        }
    }
#pragma unroll
    for (int k = 0; k < 2; k++)
#pragma unroll
        for (int j = 0; j < 4; j++) mu2_ws[((size_t)b * 2 + k) * 256 + lane + 64 * j] = mu[k][j];
}

// ---------------- P1 = softmax(q.m1), P2 = softmax(q.mu2) ----------------
__global__ __launch_bounds__(256) void pmap_k(
    const float* __restrict__ query, const float* __restrict__ m1_ws,
    const float* __restrict__ mu2_ws, float* __restrict__ P1, float* __restrict__ P2)
{
    __shared__ float ms[7 * 256];
    int b = blockIdx.y;
    int t = threadIdx.x;
    int n = blockIdx.x * 256 + t;
    for (int idx = t; idx < 1280; idx += 256) ms[idx] = m1_ws[(size_t)b * 1280 + idx];
    for (int idx = t; idx < 512; idx += 256) ms[1280 + idx] = mu2_ws[(size_t)b * 512 + idx];
    __syncthreads();
    const float* qrow = query + ((size_t)b * NN + n) * ND;
    float lg[7] = {0,0,0,0,0,0,0};
    for (int c4 = 0; c4 < 256; c4 += 4) {
        float4 qv = *(const float4*)&qrow[c4];
#pragma unroll
        for (int k = 0; k < 7; k++) {
            float4 mv = *(const float4*)&ms[k * 256 + c4];
            lg[k] += qv.x*mv.x + qv.y*mv.y + qv.z*mv.z + qv.w*mv.w;
        }
    }
    float mx = lg[0];
#pragma unroll
    for (int k = 1; k < 5; k++) mx = fmaxf(mx, lg[k]);
    float e[5], ssum = 0.f;
#pragma unroll
    for (int k = 0; k < 5; k++) { e[k] = expf(lg[k] - mx); ssum += e[k]; }
    float is = 1.0f / ssum;
#pragma unroll
    for (int k = 0; k < 5; k++) P1[((size_t)b * 5 + k) * NN + n] = e[k] * is;
    float mx2 = fmaxf(lg[5], lg[6]);
    float e0 = expf(lg[5] - mx2), e1 = expf(lg[6] - mx2);
    float inv = 1.0f / (e0 + e1);
    P2[((size_t)b * 2 + 0) * NN + n] = e0 * inv;
    P2[((size_t)b * 2 + 1) * NN + n] = e1 * inv;
}

// ---------------- node_weight conv: one (b, ch) per block, 3 barriers total ----------------
__global__ __launch_bounds__(1024) void nwconv_k(
    const float* __restrict__ P1, const float* __restrict__ P2,
    const float* __restrict__ w1a, const float* __restrict__ b1a,
    const float* __restrict__ ga,  const float* __restrict__ bea,
    const float* __restrict__ w2a, const float* __restrict__ b2a,
    const float* __restrict__ w1b, const float* __restrict__ b1b,
    const float* __restrict__ gb,  const float* __restrict__ beb,
    const float* __restrict__ w2b, const float* __restrict__ b2b,
    float* __restrict__ out)
{
    __shared__ float img[34 * 34];
    __shared__ float mid[16][34 * 34];
    __shared__ float w1s[144], w2s[144], bs[16], gs[16], bes[16], b2s[1];
    int ch = blockIdx.x, b = blockIdx.y;
    int t = threadIdx.x;
    int i = t >> 5, j = t & 31;
    const float* xsrc = (ch < 5) ? &P1[((size_t)b * 5 + ch) * NN]
                                 : &P2[((size_t)b * 2 + (ch - 5)) * NN];
    if (t < 144) { w1s[t] = (ch < 5 ? w1a : w1b)[t]; w2s[t] = (ch < 5 ? w2a : w2b)[t]; }
    if (t >= 256 && t < 272) {
        int y = t - 256;
        bs[y] = (ch < 5 ? b1a : b1b)[y];
        gs[y] = (ch < 5 ? ga : gb)[y];
        bes[y] = (ch < 5 ? bea : beb)[y];
    }
    if (t == 512) b2s[0] = (ch < 5 ? b2a : b2b)[0];
    for (int idx = t; idx < 1156; idx += 1024) img[idx] = 0.f;
    for (int idx = t; idx < 16 * 1156; idx += 1024) ((float*)mid)[idx] = 0.f;
    __syncthreads();
    float xv = xsrc[t];
    img[(i + 1) * 34 + (j + 1)] = xv;
    __syncthreads();
    float r[9];
#pragma unroll
    for (int dy = 0; dy < 3; dy++)
#pragma unroll
        for (int dx = 0; dx < 3; dx++)
            r[dy * 3 + dx] = img[(i + dy) * 34 + (j + dx)];
    const float bninv = rsqrtf(1.0f + 1e-5f);
#pragma unroll
    for (int oc = 0; oc < 16; oc++) {
        float a = 0.f;
#pragma unroll
        for (int q2 = 0; q2 < 9; q2++) a += w1s[oc * 9 + q2] * r[q2];
        a += bs[oc];
        a = gs[oc] * (a * bninv) + bes[oc];
        a = fmaxf(a, 0.f);
        mid[oc][(i + 1) * 34 + (j + 1)] = a;
    }
    __syncthreads();
    float acc2 = b2s[0];
#pragma unroll
    for (int oc = 0; oc < 16; oc++)
#pragma unroll
        for (int dy = 0; dy < 3; dy++)
#pragma unroll
            for (int dx = 0; dx < 3; dx++)
                acc2 += w2s[oc * 9 + dy * 3 + dx] * mid[oc][(i + dy) * 34 + (j + dx)];
    float sig = 1.0f / (1.0f + expf(-acc2));
    out[((size_t)(b * NN + t)) * 8 + 1 + ch] = xv * sig;
}

extern "C" void kernel_launch(void* const* d_in, const int* in_sizes, int n_in,
                              void* d_out, int out_size, void* d_ws, size_t ws_size,
                              hipStream_t stream) {
    const float* query = (const float*)d_in[0];
    const float* key   = (const float*)d_in[1];
    const float* value = (const float*)d_in[2];
    const float* lamda = (const float*)d_in[3];
    const float* W0 = (const float*)d_in[4];
    const float* b0 = (const float*)d_in[5];
    const float* W1 = (const float*)d_in[6];
    const float* b1 = (const float*)d_in[7];
    const float* mu_a = (const float*)d_in[8];
    const float* mu_b = (const float*)d_in[9];
    const float* nw1_w1 = (const float*)d_in[10];
    const float* nw1_b1 = (const float*)d_in[11];
    const float* nw1_g  = (const float*)d_in[12];
    const float* nw1_be = (const float*)d_in[13];
    const float* nw1_w2 = (const float*)d_in[14];
    const float* nw1_b2 = (const float*)d_in[15];
    const float* nw2_w1 = (const float*)d_in[16];
    const float* nw2_b1 = (const float*)d_in[17];
    const float* nw2_g  = (const float*)d_in[18];
    const float* nw2_be = (const float*)d_in[19];
    const float* nw2_w2 = (const float*)d_in[20];
    const float* nw2_b2 = (const float*)d_in[21];
    float* out = (float*)d_out;

    // ws: QLb [0,8MB) + KLb [8,16MB) as bf16 (attention path).
    bf* QLb = (bf*)d_ws;
    bf* KLb = (bf*)((char*)d_ws + ((size_t)8 << 20));
    // PMMS scratch (~3.2 MB) OVERLAYS the QLb region. Safe: attn3_k (last consumer of
    // QLb/KLb) completes before the first pmms_a_k launch on the serialized stream.
    float* PA   = (float*)d_ws;
    float* PB   = PA + (size_t)16 * 16 * PSTRIDE;
    float* m1w  = PB + (size_t)16 * 16 * PSTRIDE;
    float* mu2w = m1w + (size_t)16 * 1280;
    float* P1w  = mu2w + (size_t)16 * 512;
    float* P2w  = P1w + (size_t)16 * 5 * 1024;

    zero_k<<<16, 1024, 0, stream>>>(out);
    gemm_k<<<dim3(256, 4, 2), 256, 0, stream>>>(query, key, W0, b0, W1, b1, QLb, KLb);
    attn3_k<<<dim3(128, 4), 256, 0, stream>>>(QLb, KLb, value, lamda, out);
    for (int s = 0; s < 10; s++) {
        const float* pin = (s & 1) ? PA : PB;
        float* pout      = (s & 1) ? PB : PA;
        pmms_a_k<<<dim3(16, 16), 256, 0, stream>>>(query, mu_a, pin, pout, s);
    }
    pmms_b_k<<<16, 64, 0, stream>>>(PB, mu_b, m1w, mu2w);
    pmap_k<<<dim3(4, 16), 256, 0, stream>>>(query, m1w, mu2w, P1w, P2w);
    nwconv_k<<<dim3(7, 16), 1024, 0, stream>>>(P1w, P2w,
                                    nw1_w1, nw1_b1, nw1_g, nw1_be, nw1_w2, nw1_b2,
                                    nw2_w1, nw2_b1, nw2_g, nw2_be, nw2_w2, nw2_b2, out);
}

// Round 3
// 397.141 us; speedup vs baseline: 3.0215x; 1.0735x over previous
//
#include <hip/hip_runtime.h>
#include <hip/hip_bf16.h>
#include <math.h>

#define NN 1024
#define ND 256
#define PSTRIDE 1288   // per-(b,chunk) partial block: 5*256 mu-acc + 5 colsum + pad

typedef __hip_bfloat16 bf;
__device__ __forceinline__ float bf2f(bf h) { return __bfloat162float(h); }

typedef __attribute__((ext_vector_type(8))) short bf16x8;
typedef __attribute__((ext_vector_type(4))) float f32x4;

__device__ __forceinline__ float wave_reduce_sum(float v) {
#pragma unroll
    for (int off = 32; off > 0; off >>= 1) v += __shfl_down(v, off, 64);
    return v;
}
__device__ __forceinline__ float wave_allreduce_sum(float v) {
#pragma unroll
    for (int off = 1; off < 64; off <<= 1) v += __shfl_xor(v, off, 64);
    return v;
}

__global__ void zero_k(float* __restrict__ out) {
    int i = blockIdx.x * 1024 + threadIdx.x;
    out[(size_t)i * 8] = 0.f;
}

// ---------------- split-bf16 MFMA GEMM: QL = query@W0^T+b0 ; KL = key@W1^T+b1 ----------------
// a = ah + al (two bf16), a.w ~= ah.wh + ah.wl + al.wh  (lo.lo dropped, ~2^-18 rel).
// Block: 64 rows x 256 cols, 4 waves (wave w -> cols w*64..+63, 4x4 16x16 frags).
// LDS staged in MFMA fragment order -> lane-linear ds_read_b128, zero bank conflicts.
__global__ __launch_bounds__(256) void gemm2_k(
    const float* __restrict__ Aq, const float* __restrict__ Ak,
    const float* __restrict__ W0, const float* __restrict__ b0v,
    const float* __restrict__ W1, const float* __restrict__ b1v,
    bf* __restrict__ QL, bf* __restrict__ KL)
{
    const float* A; const float* Bw; const float* bias; bf* C;
    if (blockIdx.z == 0) { A = Aq; Bw = W0; bias = b0v; C = QL; }
    else                 { A = Ak; Bw = W1; bias = b1v; C = KL; }
    __shared__ short Ahi[4 * 64 * 8],  Alo[4 * 64 * 8];    // 4 m-frags
    __shared__ short Bhi[16 * 64 * 8], Blo[16 * 64 * 8];   // 16 n-frags
    const int t = threadIdx.x;
    const int wave = t >> 6, lane = t & 63;
    const int m0 = blockIdx.x * 64;

    f32x4 acc[4][4];
#pragma unroll
    for (int m = 0; m < 4; m++)
#pragma unroll
        for (int n = 0; n < 4; n++)
#pragma unroll
            for (int r = 0; r < 4; r++) acc[m][n][r] = 0.f;

    for (int k0 = 0; k0 < 256; k0 += 32) {
        __syncthreads();
        // stage A: slot t -> m-frag t>>6, lane t&63; row m0+(fm*16)+(l&15), k k0+(l>>4)*8
        {
            int fm = t >> 6, ls = t & 63;
            const float* src = A + (size_t)(m0 + fm * 16 + (ls & 15)) * 256 + k0 + ((ls >> 4) * 8);
            float4 x = *(const float4*)src;
            float4 y = *(const float4*)(src + 4);
            float v[8] = {x.x, x.y, x.z, x.w, y.x, y.y, y.z, y.w};
            short h[8], l8[8];
#pragma unroll
            for (int j = 0; j < 8; j++) {
                bf hb = __float2bfloat16(v[j]);
                float hf = __bfloat162float(hb);
                bf lb = __float2bfloat16(v[j] - hf);
                h[j] = *(short*)&hb; l8[j] = *(short*)&lb;
            }
            *(bf16x8*)&Ahi[t * 8] = *(bf16x8*)h;
            *(bf16x8*)&Alo[t * 8] = *(bf16x8*)l8;
        }
        // stage B (W): 1024 slots, 4 per thread
#pragma unroll
        for (int i = 0; i < 4; i++) {
            int idx = t + i * 256;
            int nf = idx >> 6, ls = idx & 63;
            const float* src = Bw + (size_t)(nf * 16 + (ls & 15)) * 256 + k0 + ((ls >> 4) * 8);
            float4 x = *(const float4*)src;
            float4 y = *(const float4*)(src + 4);
            float v[8] = {x.x, x.y, x.z, x.w, y.x, y.y, y.z, y.w};
            short h[8], l8[8];
#pragma unroll
            for (int j = 0; j < 8; j++) {
                bf hb = __float2bfloat16(v[j]);
                float hf = __bfloat162float(hb);
                bf lb = __float2bfloat16(v[j] - hf);
                h[j] = *(short*)&hb; l8[j] = *(short*)&lb;
            }
            *(bf16x8*)&Bhi[idx * 8] = *(bf16x8*)h;
            *(bf16x8*)&Blo[idx * 8] = *(bf16x8*)l8;
        }
        __syncthreads();
        bf16x8 ah[4], al[4], bh[4], bl[4];
#pragma unroll
        for (int m = 0; m < 4; m++) {
            ah[m] = *(const bf16x8*)&Ahi[(m * 64 + lane) * 8];
            al[m] = *(const bf16x8*)&Alo[(m * 64 + lane) * 8];
        }
#pragma unroll
        for (int n = 0; n < 4; n++) {
            int nf = wave * 4 + n;
            bh[n] = *(const bf16x8*)&Bhi[(nf * 64 + lane) * 8];
            bl[n] = *(const bf16x8*)&Blo[(nf * 64 + lane) * 8];
        }
#pragma unroll
        for (int m = 0; m < 4; m++)
#pragma unroll
            for (int n = 0; n < 4; n++) {
                acc[m][n] = __builtin_amdgcn_mfma_f32_16x16x32_bf16(ah[m], bh[n], acc[m][n], 0, 0, 0);
                acc[m][n] = __builtin_amdgcn_mfma_f32_16x16x32_bf16(ah[m], bl[n], acc[m][n], 0, 0, 0);
                acc[m][n] = __builtin_amdgcn_mfma_f32_16x16x32_bf16(al[m], bh[n], acc[m][n], 0, 0, 0);
            }
    }
    // epilogue: C layout col = lane&15, row = (lane>>4)*4 + r
#pragma unroll
    for (int n = 0; n < 4; n++) {
        int col = (wave * 4 + n) * 16 + (lane & 15);
        float bv = bias[col];
#pragma unroll
        for (int m = 0; m < 4; m++) {
            int row = m0 + m * 16 + (lane >> 4) * 4;
#pragma unroll
            for (int r = 0; r < 4; r++) {
                bf hv = __float2bfloat16(acc[m][n][r] + bv);
                C[(size_t)(row + r) * 256 + col] = hv;
            }
        }
    }
}

// ---------------- MFMA flash attention from materialized bf16 QL/KL ----------------
__global__ __launch_bounds__(256) void attn3_k(
    const bf* __restrict__ QL, const bf* __restrict__ KL,
    const float* __restrict__ value, const float* __restrict__ lamda,
    float* __restrict__ out)
{
    const int bh = blockIdx.x; const int b = bh >> 3, h = bh & 7;
    const int t = threadIdx.x;
    const int wave = t >> 6, lane = t & 63;
    const int q0 = blockIdx.y * 256 + wave * 64;
    const float scale = 0.17677669529663687f;

    __shared__ bf Kf[128 * 32];   // 512 fragments * 8 bf16, fragment order
    __shared__ float vv[128];

    bf16x8 qf[4];
    {
        const bf* qbase = QL + ((size_t)b * NN) * ND + h * 32 + (lane >> 4) * 8;
#pragma unroll
        for (int m = 0; m < 4; m++)
            qf[m] = *(const bf16x8*)(qbase + (size_t)(q0 + m * 16 + (lane & 15)) * ND);
    }
    f32x4 lsum[4], vacc[4], wacc[4];
#pragma unroll
    for (int m = 0; m < 4; m++)
#pragma unroll
        for (int r = 0; r < 4; r++) { lsum[m][r] = 0.f; vacc[m][r] = 0.f; wacc[m][r] = 0.f; }

    const bf* kbase = KL + ((size_t)b * NN) * ND + h * 32;
    for (int kt = 0; kt < 8; kt++) {
        const int k0 = kt * 128;
        __syncthreads();
#pragma unroll
        for (int i = 0; i < 2; i++) {
            int f = t + i * 256;
            int row = ((f >> 6) << 4) + (f & 15);
            int chunk = (f >> 4) & 3;
            *(bf16x8*)&Kf[f * 8] = *(const bf16x8*)(kbase + (size_t)(k0 + row) * ND + chunk * 8);
        }
        if (t < 128) vv[t] = value[(size_t)b * NN + k0 + t];
        __syncthreads();
#pragma unroll
        for (int s = 0; s < 8; s++) {
            bf16x8 bfr = *(const bf16x8*)&Kf[(s * 64 + lane) * 8];
            float vcol = vv[s * 16 + (lane & 15)];
#pragma unroll
            for (int m = 0; m < 4; m++) {
                f32x4 acc = {0.f, 0.f, 0.f, 0.f};
                acc = __builtin_amdgcn_mfma_f32_16x16x32_bf16(qf[m], bfr, acc, 0, 0, 0);
#pragma unroll
                for (int r = 0; r < 4; r++) {
                    float sraw = acc[r];
                    float p = __expf(sraw * scale);
                    lsum[m][r] += p;
                    vacc[m][r] += p * vcol;
                    wacc[m][r] += sraw * vcol;
                }
            }
        }
    }
    const float lam = lamda[0];
#pragma unroll
    for (int m = 0; m < 4; m++)
#pragma unroll
        for (int r = 0; r < 4; r++) {
            float ls = lsum[m][r], va = vacc[m][r], wa = wacc[m][r];
#pragma unroll
            for (int off = 1; off < 16; off <<= 1) {
                ls += __shfl_xor(ls, off, 64);
                va += __shfl_xor(va, off, 64);
                wa += __shfl_xor(wa, off, 64);
            }
            if ((lane & 15) == 0) {
                int q = q0 + m * 16 + (lane >> 4) * 4 + r;
                float part = va / ls;
                float whole = fmaxf(wa * scale * (1.0f / 1024.0f), 0.f);
                float f = ((1.f - lam) * part + lam * whole) * 0.125f;
                atomicAdd(&out[((size_t)b * NN + q) * 8], f);
            }
        }
}

// ---------------- one phase-A PMMS stage: grid (16 chunks, 16 batches) x 256 ----------------
// query block (64x256) staged in LDS once (padded stride 260 -> conflict-free both passes).
__global__ __launch_bounds__(256) void pmms_a_k(
    const float* __restrict__ query, const float* __restrict__ mu0a,
    const float* __restrict__ pin, float* __restrict__ pout, int stage)
{
    __shared__ float qs[64 * 260];    // 64 rows x 256 cols, stride 260 (1040B, 16B-aligned)
    __shared__ float muT[5 * 256];    // [k][c]
    __shared__ float z_s[64][8];      // [n_local][k]
    __shared__ float red[32];
    int chunk = blockIdx.x, b = blockIdx.y;
    int t = threadIdx.x;
    int wave = t >> 6, lane = t & 63;

    // stage q block (coalesced float4)
    {
        const float* qg = query + ((size_t)b * NN + chunk * 64) * ND;
        for (int i = t; i < 4096; i += 256) {
            int row = i >> 6, c4 = (i & 63) * 4;
            *(float4*)&qs[row * 260 + c4] = *(const float4*)&qg[(size_t)row * ND + c4];
        }
    }

    if (stage == 0) {
        for (int idx = t; idx < 1280; idx += 256)
            muT[idx] = mu0a[(idx & 255) * 5 + (idx >> 8)];
    } else {
        float mr[5] = {0,0,0,0,0};
        float cs[5] = {0,0,0,0,0};
        for (int ch = 0; ch < 16; ch++) {
            const float* pb = pin + ((size_t)(b * 16 + ch)) * PSTRIDE;
#pragma unroll
            for (int k = 0; k < 5; k++) mr[k] += pb[k * 256 + t];
#pragma unroll
            for (int k = 0; k < 5; k++) cs[k] += pb[1280 + k];
        }
#pragma unroll
        for (int k = 0; k < 5; k++) mr[k] *= 1.0f / (1e-6f + cs[k]);
#pragma unroll
        for (int k = 0; k < 5; k++) {
            float s = wave_reduce_sum(mr[k] * mr[k]);
            if (lane == 0) red[wave * 5 + k] = s;
        }
        __syncthreads();
        if (t < 5) red[20 + t] = 1.0f / (1e-6f + sqrtf(red[t] + red[5 + t] + red[10 + t] + red[15 + t]));
        __syncthreads();
#pragma unroll
        for (int k = 0; k < 5; k++) muT[k * 256 + t] = mr[k] * red[20 + k];
    }
    __syncthreads();

    // z for 64 rows: 4 lanes per row, each covering 64 c's (from LDS)
    int n_local = t >> 2, part = t & 3;
    const float* qrow = &qs[n_local * 260 + part * 64];
    float lg[5] = {0,0,0,0,0};
#pragma unroll
    for (int c4 = 0; c4 < 64; c4 += 4) {
        float4 qv = *(const float4*)&qrow[c4];
#pragma unroll
        for (int k = 0; k < 5; k++) {
            float4 mv = *(const float4*)&muT[k * 256 + part * 64 + c4];
            lg[k] += qv.x*mv.x + qv.y*mv.y + qv.z*mv.z + qv.w*mv.w;
        }
    }
#pragma unroll
    for (int k = 0; k < 5; k++) {
        lg[k] += __shfl_xor(lg[k], 1, 64);
        lg[k] += __shfl_xor(lg[k], 2, 64);
    }
    float mx = lg[0];
#pragma unroll
    for (int k = 1; k < 5; k++) mx = fmaxf(mx, lg[k]);
    float e[5], ssum = 0.f;
#pragma unroll
    for (int k = 0; k < 5; k++) { e[k] = expf(20.0f * (lg[k] - mx)); ssum += e[k]; }
    float is = 1.0f / ssum;
    if (part == 0) {
#pragma unroll
        for (int k = 0; k < 5; k++) z_s[n_local][k] = e[k] * is;
    }
    __syncthreads();

    // partial mu accumulation: thread owns c = t (col-pass from LDS, conflict-free)
    float pa[5] = {0,0,0,0,0};
#pragma unroll 4
    for (int nl = 0; nl < 64; nl++) {
        float qv = qs[nl * 260 + t];
        float4 z4 = *(const float4*)&z_s[nl][0];
        float z4v = z_s[nl][4];
        pa[0] += qv * z4.x; pa[1] += qv * z4.y; pa[2] += qv * z4.z;
        pa[3] += qv * z4.w; pa[4] += qv * z4v;
    }
    float* pb = pout + ((size_t)(b * 16 + chunk)) * PSTRIDE;
#pragma unroll
    for (int k = 0; k < 5; k++) pb[k * 256 + t] = pa[k];
    if (t < 5) {
        float s = 0.f;
        for (int nl = 0; nl < 64; nl++) s += z_s[nl][t];
        pb[1280 + t] = s;
    }
}

// ---------------- phase B: wave-synchronous, one 64-thread block per batch ----------------
__global__ __launch_bounds__(64) void pmms_b_k(
    const float* __restrict__ pin, const float* __restrict__ mu0b,
    float* __restrict__ m1_ws, float* __restrict__ mu2_ws)
{
    int b = blockIdx.x, lane = threadIdx.x;
    float nd[5][4];
    float cs[5] = {0,0,0,0,0};
#pragma unroll
    for (int n = 0; n < 5; n++)
#pragma unroll
        for (int j = 0; j < 4; j++) nd[n][j] = 0.f;
    for (int ch = 0; ch < 16; ch++) {
        const float* pb = pin + ((size_t)(b * 16 + ch)) * PSTRIDE;
#pragma unroll
        for (int n = 0; n < 5; n++)
#pragma unroll
            for (int j = 0; j < 4; j++) nd[n][j] += pb[n * 256 + lane + 64 * j];
#pragma unroll
        for (int n = 0; n < 5; n++) cs[n] += pb[1280 + n];
    }
#pragma unroll
    for (int n = 0; n < 5; n++) {
        float inv = 1.0f / (1e-6f + cs[n]);
        float sq = 0.f;
#pragma unroll
        for (int j = 0; j < 4; j++) { nd[n][j] *= inv; sq += nd[n][j] * nd[n][j]; }
        float s = wave_allreduce_sum(sq);
        float nr = 1.0f / (1e-6f + sqrtf(s));
#pragma unroll
        for (int j = 0; j < 4; j++) {
            nd[n][j] *= nr;
            m1_ws[((size_t)b * 5 + n) * 256 + lane + 64 * j] = nd[n][j];
        }
    }
    float mu[2][4];
#pragma unroll
    for (int k = 0; k < 2; k++)
#pragma unroll
        for (int j = 0; j < 4; j++) mu[k][j] = mu0b[(lane + 64 * j) * 2 + k];
    for (int stage = 0; stage < 10; stage++) {
        float z[5][2];
        float colsum0 = 0.f, colsum1 = 0.f;
#pragma unroll
        for (int n = 0; n < 5; n++) {
            float l0 = 0.f, l1 = 0.f;
#pragma unroll
            for (int j = 0; j < 4; j++) { l0 += nd[n][j] * mu[0][j]; l1 += nd[n][j] * mu[1][j]; }
            l0 = wave_allreduce_sum(l0);
            l1 = wave_allreduce_sum(l1);
            float a0 = 20.0f * l0, a1 = 20.0f * l1;
            float mxv = fmaxf(a0, a1);
            float e0 = expf(a0 - mxv), e1 = expf(a1 - mxv);
            float inv = 1.0f / (e0 + e1);
            z[n][0] = e0 * inv; z[n][1] = e1 * inv;
            colsum0 += z[n][0]; colsum1 += z[n][1];
        }
        float i0 = 1.0f / (1e-6f + colsum0), i1 = 1.0f / (1e-6f + colsum1);
#pragma unroll
        for (int k = 0; k < 2; k++) {
            float iv = k ? i1 : i0;
            float sq = 0.f;
            float nm[4];
#pragma unroll
            for (int j = 0; j < 4; j++) {
                float v = 0.f;
#pragma unroll
                for (int n = 0; n < 5; n++) v += nd[n][j] * z[n][k];
                v *= iv;
                nm[j] = v; sq += v * v;
            }
            float s = wave_allreduce_sum(sq);
            float nr = 1.0f / (1e-6f + sqrtf(s));
#pragma unroll
            for (int j = 0; j < 4; j++) mu[k][j] = nm[j] * nr;
        }
    }
#pragma unroll
    for (int k = 0; k < 2; k++)
#pragma unroll
        for (int j = 0; j < 4; j++) mu2_ws[((size_t)b * 2 + k) * 256 + lane + 64 * j] = mu[k][j];
}

// ---------------- P1 = softmax(q.m1), P2 = softmax(q.mu2) ----------------
__global__ __launch_bounds__(256) void pmap_k(
    const float* __restrict__ query, const float* __restrict__ m1_ws,
    const float* __restrict__ mu2_ws, float* __restrict__ P1, float* __restrict__ P2)
{
    __shared__ float ms[7 * 256];
    int b = blockIdx.y;
    int t = threadIdx.x;
    int n = blockIdx.x * 256 + t;
    for (int idx = t; idx < 1280; idx += 256) ms[idx] = m1_ws[(size_t)b * 1280 + idx];
    for (int idx = t; idx < 512; idx += 256) ms[1280 + idx] = mu2_ws[(size_t)b * 512 + idx];
    __syncthreads();
    const float* qrow = query + ((size_t)b * NN + n) * ND;
    float lg[7] = {0,0,0,0,0,0,0};
    for (int c4 = 0; c4 < 256; c4 += 4) {
        float4 qv = *(const float4*)&qrow[c4];
#pragma unroll
        for (int k = 0; k < 7; k++) {
            float4 mv = *(const float4*)&ms[k * 256 + c4];
            lg[k] += qv.x*mv.x + qv.y*mv.y + qv.z*mv.z + qv.w*mv.w;
        }
    }
    float mx = lg[0];
#pragma unroll
    for (int k = 1; k < 5; k++) mx = fmaxf(mx, lg[k]);
    float e[5], ssum = 0.f;
#pragma unroll
    for (int k = 0; k < 5; k++) { e[k] = expf(lg[k] - mx); ssum += e[k]; }
    float is = 1.0f / ssum;
#pragma unroll
    for (int k = 0; k < 5; k++) P1[((size_t)b * 5 + k) * NN + n] = e[k] * is;
    float mx2 = fmaxf(lg[5], lg[6]);
    float e0 = expf(lg[5] - mx2), e1 = expf(lg[6] - mx2);
    float inv = 1.0f / (e0 + e1);
    P2[((size_t)b * 2 + 0) * NN + n] = e0 * inv;
    P2[((size_t)b * 2 + 1) * NN + n] = e1 * inv;
}

// ---------------- node_weight conv: one (b, ch) per block, 3 barriers total ----------------
__global__ __launch_bounds__(1024) void nwconv_k(
    const float* __restrict__ P1, const float* __restrict__ P2,
    const float* __restrict__ w1a, const float* __restrict__ b1a,
    const float* __restrict__ ga,  const float* __restrict__ bea,
    const float* __restrict__ w2a, const float* __restrict__ b2a,
    const float* __restrict__ w1b, const float* __restrict__ b1b,
    const float* __restrict__ gb,  const float* __restrict__ beb,
    const float* __restrict__ w2b, const float* __restrict__ b2b,
    float* __restrict__ out)
{
    __shared__ float img[34 * 34];
    __shared__ float mid[16][34 * 34];
    __shared__ float w1s[144], w2s[144], bs[16], gs[16], bes[16], b2s[1];
    int ch = blockIdx.x, b = blockIdx.y;
    int t = threadIdx.x;
    int i = t >> 5, j = t & 31;
    const float* xsrc = (ch < 5) ? &P1[((size_t)b * 5 + ch) * NN]
                                 : &P2[((size_t)b * 2 + (ch - 5)) * NN];
    if (t < 144) { w1s[t] = (ch < 5 ? w1a : w1b)[t]; w2s[t] = (ch < 5 ? w2a : w2b)[t]; }
    if (t >= 256 && t < 272) {
        int y = t - 256;
        bs[y] = (ch < 5 ? b1a : b1b)[y];
        gs[y] = (ch < 5 ? ga : gb)[y];
        bes[y] = (ch < 5 ? bea : beb)[y];
    }
    if (t == 512) b2s[0] = (ch < 5 ? b2a : b2b)[0];
    for (int idx = t; idx < 1156; idx += 1024) img[idx] = 0.f;
    for (int idx = t; idx < 16 * 1156; idx += 1024) ((float*)mid)[idx] = 0.f;
    __syncthreads();
    float xv = xsrc[t];
    img[(i + 1) * 34 + (j + 1)] = xv;
    __syncthreads();
    float r[9];
#pragma unroll
    for (int dy = 0; dy < 3; dy++)
#pragma unroll
        for (int dx = 0; dx < 3; dx++)
            r[dy * 3 + dx] = img[(i + dy) * 34 + (j + dx)];
    const float bninv = rsqrtf(1.0f + 1e-5f);
#pragma unroll
    for (int oc = 0; oc < 16; oc++) {
        float a = 0.f;
#pragma unroll
        for (int q2 = 0; q2 < 9; q2++) a += w1s[oc * 9 + q2] * r[q2];
        a += bs[oc];
        a = gs[oc] * (a * bninv) + bes[oc];
        a = fmaxf(a, 0.f);
        mid[oc][(i + 1) * 34 + (j + 1)] = a;
    }
    __syncthreads();
    float acc2 = b2s[0];
#pragma unroll
    for (int oc = 0; oc < 16; oc++)
#pragma unroll
        for (int dy = 0; dy < 3; dy++)
#pragma unroll
            for (int dx = 0; dx < 3; dx++)
                acc2 += w2s[oc * 9 + dy * 3 + dx] * mid[oc][(i + dy) * 34 + (j + dx)];
    float sig = 1.0f / (1.0f + expf(-acc2));
    out[((size_t)(b * NN + t)) * 8 + 1 + ch] = xv * sig;
}

extern "C" void kernel_launch(void* const* d_in, const int* in_sizes, int n_in,
                              void* d_out, int out_size, void* d_ws, size_t ws_size,
                              hipStream_t stream) {
    const float* query = (const float*)d_in[0];
    const float* key   = (const float*)d_in[1];
    const float* value = (const float*)d_in[2];
    const float* lamda = (const float*)d_in[3];
    const float* W0 = (const float*)d_in[4];
    const float* b0 = (const float*)d_in[5];
    const float* W1 = (const float*)d_in[6];
    const float* b1 = (const float*)d_in[7];
    const float* mu_a = (const float*)d_in[8];
    const float* mu_b = (const float*)d_in[9];
    const float* nw1_w1 = (const float*)d_in[10];
    const float* nw1_b1 = (const float*)d_in[11];
    const float* nw1_g  = (const float*)d_in[12];
    const float* nw1_be = (const float*)d_in[13];
    const float* nw1_w2 = (const float*)d_in[14];
    const float* nw1_b2 = (const float*)d_in[15];
    const float* nw2_w1 = (const float*)d_in[16];
    const float* nw2_b1 = (const float*)d_in[17];
    const float* nw2_g  = (const float*)d_in[18];
    const float* nw2_be = (const float*)d_in[19];
    const float* nw2_w2 = (const float*)d_in[20];
    const float* nw2_b2 = (const float*)d_in[21];
    float* out = (float*)d_out;

    // ws: QLb [0,8MB) + KLb [8,16MB) as bf16 (attention path).
    bf* QLb = (bf*)d_ws;
    bf* KLb = (bf*)((char*)d_ws + ((size_t)8 << 20));
    // PMMS scratch (~3.2 MB) OVERLAYS the QLb region. Safe: attn3_k (last consumer of
    // QLb/KLb) completes before the first pmms_a_k launch on the serialized stream.
    float* PA   = (float*)d_ws;
    float* PB   = PA + (size_t)16 * 16 * PSTRIDE;
    float* m1w  = PB + (size_t)16 * 16 * PSTRIDE;
    float* mu2w = m1w + (size_t)16 * 1280;
    float* P1w  = mu2w + (size_t)16 * 512;
    float* P2w  = P1w + (size_t)16 * 5 * 1024;

    zero_k<<<16, 1024, 0, stream>>>(out);
    gemm2_k<<<dim3(256, 1, 2), 256, 0, stream>>>(query, key, W0, b0, W1, b1, QLb, KLb);
    attn3_k<<<dim3(128, 4), 256, 0, stream>>>(QLb, KLb, value, lamda, out);
    for (int s = 0; s < 10; s++) {
        const float* pin = (s & 1) ? PA : PB;
        float* pout      = (s & 1) ? PB : PA;
        pmms_a_k<<<dim3(16, 16), 256, 0, stream>>>(query, mu_a, pin, pout, s);
    }
    pmms_b_k<<<16, 64, 0, stream>>>(PB, mu_b, m1w, mu2w);
    pmap_k<<<dim3(4, 16), 256, 0, stream>>>(query, m1w, mu2w, P1w, P2w);
    nwconv_k<<<dim3(7, 16), 1024, 0, stream>>>(P1w, P2w,
                                    nw1_w1, nw1_b1, nw1_g, nw1_be, nw1_w2, nw1_b2,
                                    nw2_w1, nw2_b1, nw2_g, nw2_be, nw2_w2, nw2_b2, out);
}